// Round 4
// baseline (195.752 us; speedup 1.0000x reference)
//
#include <hip/hip_runtime.h>
#include <math.h>

#define T_ 768
#define TD (T_*64)
#define EPSF 1e-8f

typedef __attribute__((ext_vector_type(8))) short short8;
typedef __attribute__((ext_vector_type(4))) float f32x4;

__device__ __forceinline__ float wave_sum64(float v) {
#pragma unroll
  for (int m = 32; m >= 1; m >>= 1) v += __shfl_xor(v, m, 64);
  return v;
}
__device__ __forceinline__ float wave_max64(float v) {
#pragma unroll
  for (int m = 32; m >= 1; m >>= 1) v = fmaxf(v, __shfl_xor(v, m, 64));
  return v;
}
__device__ __forceinline__ float sigmoidf_(float x) { return 1.0f / (1.0f + expf(-x)); }

__device__ __forceinline__ unsigned short f2bf(float x) {
  unsigned int u = __float_as_uint(x);
  u += 0x7fffu + ((u >> 16) & 1u);        // RNE
  return (unsigned short)(u >> 16);
}

// acos(x) for x in [0,1): sqrt(1-x)*(a0+a1 x+a2 x^2+a3 x^3), |err|<=6.7e-5 (A-S 4.4.45)
__device__ __forceinline__ float acos_pos(float x) {
  float s = sqrtf(fmaxf(1.0f - x, 0.0f));
  return s * (1.5707288f + x * (-0.2121144f + x * (0.0742610f + x * (-0.0187293f))));
}

// simplex proj + renorm; write feature row f=[sqrt(p), sqrt(eps/2)/sqrt(p)] bf16
__device__ __forceinline__ void feat_bf(float v, int row, int lane,
                                        unsigned short* __restrict__ Fb) {
  float sp = fmaxf(v, 0.0f) + log1pf(expf(-fabsf(v)));
  float s = wave_sum64(sp);
  float p1 = fmaxf(sp / (s + EPSF), EPSF);
  float s2 = wave_sum64(p1);
  float p = p1 / (s2 + EPSF);
  Fb[row * 128 + lane] = f2bf(sqrtf(p));
  Fb[row * 128 + 64 + lane] = f2bf(sqrtf(5e-9f / p));
}

// features(bseq) + XT(bseq) + fb_w transpose + pass-0 temps. grid 192x256.
__global__ void __launch_bounds__(256)
phaseA_kernel(const float* __restrict__ bseq, const float* __restrict__ basin_coords,
              const float* __restrict__ temp_w, const float* __restrict__ temp_b,
              const float* __restrict__ fb_w,
              unsigned short* __restrict__ Fb, unsigned short* __restrict__ XTb,
              float* __restrict__ fbwT, float* __restrict__ temps) {
  int b = blockIdx.x, tid = threadIdx.x, w = tid >> 6, l = tid & 63;
  int row = b * 4 + w;
  float v = bseq[row * 64 + l];
  feat_bf(v, row, l, Fb);
  XTb[l * 768 + row] = f2bf(v);
  if (b < 128) {                         // 128*256 = 32768 = 4*64*128
    int idx = b * 256 + tid;
    int ll = idx >> 13, r = idx & 8191, d = r >> 7, k = r & 127;
    fbwT[ll * 8192 + k * 64 + d] = fb_w[ll * 8192 + d * 128 + k];
  }
  if (b == 191) {
    float t = basin_coords[l] * temp_w[w * 64 + l];
    t = wave_sum64(t);
    if (l == 0) temps[w] = sigmoidf_(t + temp_b[w]) + 0.5f;
  }
}

// Fused layer: MFMA Gram -> acos/logits -> softmax -> MFMA PV -> residual -> tail
// 48 blocks x 256 thr, 16 rows per block.
__global__ void __launch_bounds__(256)
layer_kernel(const float* __restrict__ xin,
             const unsigned short* __restrict__ Fb_in,
             const unsigned short* __restrict__ XTb_in,
             float* __restrict__ xout,
             unsigned short* __restrict__ Fb_out,
             unsigned short* __restrict__ XTb_out,
             const float* __restrict__ temps, int tidx, int lidx,
             const float* __restrict__ rs_layers, int doFeat,
             const float* __restrict__ WTnext, const float* __restrict__ bnext,
             const float* __restrict__ prevNext,
             float* __restrict__ poolPart,
             const float* __restrict__ bseq, const float* __restrict__ res_scale,
             float* __restrict__ finalOut) {
  __shared__ __align__(16) float lg[16][772];          // logits, pad: 2-way max
  __shared__ __align__(16) unsigned short Pl[16][776]; // P bf16, even bank spread
  __shared__ __align__(16) float xs[16][64];
  __shared__ __align__(16) float ps_s[16][64];
  int tid = threadIdx.x, w = tid >> 6, l = tid & 63;
  int lr = l & 15, lk = l >> 4;
  int i0 = blockIdx.x * 16;

  if (WTnext) {                          // stage prev rows early (used in tail)
#pragma unroll
    for (int rr = 0; rr < 4; rr++) {
      int row = w * 4 + rr;
      ps_s[row][l] = prevNext[(i0 + row) * 64 + l];
    }
  }

  // A-frags: lane holds F row i0+lr, k = ks*32 + lk*8 .. +7
  const short8* arow = reinterpret_cast<const short8*>(Fb_in + (i0 + lr) * 128);
  short8 afr[4];
#pragma unroll
  for (int ks = 0; ks < 4; ks++) afr[ks] = arow[ks * 4 + lk];

  float inv_t = 1.0f / fmaxf(temps[tidx], 1e-6f);

  // ---- QK Gram: wave w owns j-tiles w, w+4, ..., w+44 ----
  for (int jt = w; jt < 48; jt += 4) {
    const short8* brow = reinterpret_cast<const short8*>(Fb_in + (jt * 16 + lr) * 128);
    f32x4 acc = {0.f, 0.f, 0.f, 0.f};
#pragma unroll
    for (int ks = 0; ks < 4; ks++)
      acc = __builtin_amdgcn_mfma_f32_16x16x32_bf16(afr[ks], brow[ks * 4 + lk], acc, 0, 0, 0);
    // C layout: col = lane&15 (j within tile), row = (lane>>4)*4 + r (i)
#pragma unroll
    for (int r = 0; r < 4; r++) {
      float inner = fminf(fmaxf(acc[r], 0.0f), 1.0f - 1e-6f);
      lg[lk * 4 + r][jt * 16 + lr] = -2.0f * acos_pos(inner) * inv_t;
    }
  }
  __syncthreads();

  // ---- softmax: wave w rows 4w..4w+3, fp32, normalized bf16 P ----
#pragma unroll
  for (int rr = 0; rr < 4; rr++) {
    int row = w * 4 + rr;
    float v[12];
    float m = -1e30f;
#pragma unroll
    for (int q = 0; q < 12; q++) { v[q] = lg[row][l + 64 * q]; m = fmaxf(m, v[q]); }
    m = wave_max64(m);
    float s = 0.f;
#pragma unroll
    for (int q = 0; q < 12; q++) { v[q] = expf(v[q] - m); s += v[q]; }
    s = wave_sum64(s);
    float is = 1.0f / s;
#pragma unroll
    for (int q = 0; q < 12; q++) Pl[row][l + 64 * q] = f2bf(v[q] * is);
  }
  __syncthreads();

  // ---- PV: wave w -> output cols w*16..w*16+15; K=768 in 24 steps ----
  f32x4 pacc = {0.f, 0.f, 0.f, 0.f};
  const short8* xtrow = reinterpret_cast<const short8*>(XTb_in + (w * 16 + lr) * 768);
#pragma unroll 4
  for (int ks = 0; ks < 24; ks++) {
    short8 pa = *reinterpret_cast<const short8*>(&Pl[lr][ks * 32 + lk * 8]);
    pacc = __builtin_amdgcn_mfma_f32_16x16x32_bf16(pa, xtrow[ks * 4 + lk], pacc, 0, 0, 0);
  }
  float rs = rs_layers[lidx];
#pragma unroll
  for (int r = 0; r < 4; r++) {
    int row = lk * 4 + r, col = w * 16 + lr;
    float xi = xin[(i0 + row) * 64 + col];
    xs[row][col] = xi + rs * (pacc[r] - xi);
  }
  __syncthreads();

  // ---- tails ----
  if (finalOut) {
    float sc = 0.01f * res_scale[0];
#pragma unroll
    for (int rr = 0; rr < 4; rr++) {
      int row = w * 4 + rr;
      float xo = xs[row][l];
      finalOut[(i0 + row) * 64 + l] = xo + sc * (xo - bseq[(i0 + row) * 64 + l]);
    }
    return;
  }
  if (WTnext) {                          // feedback gate for NEXT ref-layer
    float a[4];
#pragma unroll
    for (int rr = 0; rr < 4; rr++) a[rr] = bnext[l];
    for (int k = 0; k < 64; k++) {
      float wv = WTnext[k * 64 + l];
#pragma unroll
      for (int rr = 0; rr < 4; rr++) a[rr] += xs[w * 4 + rr][k] * wv;
    }
    for (int k = 0; k < 64; k++) {
      float wv = WTnext[(64 + k) * 64 + l];
#pragma unroll
      for (int rr = 0; rr < 4; rr++) a[rr] += ps_s[w * 4 + rr][k] * wv;
    }
#pragma unroll
    for (int rr = 0; rr < 4; rr++) {
      int row = w * 4 + rr;
      float g = sigmoidf_(a[rr]);
      float xn = xs[row][l] * g + ps_s[row][l] * (1.0f - g);
      xout[(i0 + row) * 64 + l] = xn;
      XTb_out[l * 768 + i0 + row] = f2bf(xn);
      feat_bf(xn, i0 + row, l, Fb_out);
    }
  } else {
#pragma unroll
    for (int rr = 0; rr < 4; rr++) {
      int row = w * 4 + rr;
      float xo = xs[row][l];
      xout[(i0 + row) * 64 + l] = xo;
      if (doFeat) {
        XTb_out[l * 768 + i0 + row] = f2bf(xo);
        feat_bf(xo, i0 + row, l, Fb_out);
      }
    }
    if (poolPart && w == 0) {
      float s = 0.f;
#pragma unroll
      for (int r2 = 0; r2 < 16; r2++) s += xs[r2][l];
      poolPart[blockIdx.x * 64 + l] = s;
    }
  }
}

// gate(pass1,l=0) on 48 blocks; block 0 also: pool reduce -> MLP -> basin -> temps[4..7]
__global__ void __launch_bounds__(256)
compress_kernel(const float* __restrict__ xin, const float* __restrict__ prev0,
                const float* __restrict__ WT0, const float* __restrict__ b0,
                float* __restrict__ xout, unsigned short* __restrict__ Fb_out,
                unsigned short* __restrict__ XTb_out,
                const float* __restrict__ poolPart,
                const float* __restrict__ basin_coords,
                const float* __restrict__ temp_w, const float* __restrict__ temp_b,
                const float* __restrict__ w1, const float* __restrict__ b1,
                const float* __restrict__ w2, const float* __restrict__ b2,
                const float* __restrict__ uw, const float* __restrict__ ub,
                float* __restrict__ temps) {
  __shared__ float xs[16][64], ps_s[16][64];
  __shared__ float pooled[64], h1s[32], aggs[64], bnew[64];
  int tid = threadIdx.x, w = tid >> 6, l = tid & 63;
  int i0 = blockIdx.x * 16;
#pragma unroll
  for (int rr = 0; rr < 4; rr++) {
    int row = w * 4 + rr;
    xs[row][l] = xin[(i0 + row) * 64 + l];
    ps_s[row][l] = prev0[(i0 + row) * 64 + l];
  }
  __syncthreads();
  float a[4];
#pragma unroll
  for (int rr = 0; rr < 4; rr++) a[rr] = b0[l];
  for (int k = 0; k < 64; k++) {
    float wv = WT0[k * 64 + l];
#pragma unroll
    for (int rr = 0; rr < 4; rr++) a[rr] += xs[w * 4 + rr][k] * wv;
  }
  for (int k = 0; k < 64; k++) {
    float wv = WT0[(64 + k) * 64 + l];
#pragma unroll
    for (int rr = 0; rr < 4; rr++) a[rr] += ps_s[w * 4 + rr][k] * wv;
  }
#pragma unroll
  for (int rr = 0; rr < 4; rr++) {
    int row = w * 4 + rr;
    float g = sigmoidf_(a[rr]);
    float xn = xs[row][l] * g + ps_s[row][l] * (1.0f - g);
    xout[(i0 + row) * 64 + l] = xn;
    XTb_out[l * 768 + i0 + row] = f2bf(xn);
    feat_bf(xn, i0 + row, l, Fb_out);
  }
  if (blockIdx.x == 0) {
    __syncthreads();
    if (w == 0) {
      float s = 0.f;
      for (int bb = 0; bb < 48; bb++) s += poolPart[bb * 64 + l];
      pooled[l] = s * (1.0f / 768.0f);
    }
    __syncthreads();
    if (tid < 32) {
      float h = b1[tid];
      for (int k = 0; k < 64; k++) h += w1[tid * 64 + k] * pooled[k];
      h1s[tid] = tanhf(h);
    }
    __syncthreads();
    if (tid < 64) {
      float h = b2[tid];
      for (int k = 0; k < 32; k++) h += w2[tid * 32 + k] * h1s[k];
      aggs[tid] = tanhf(h);
    }
    __syncthreads();
    if (tid < 64) {
      float g = ub[tid];
      for (int k = 0; k < 64; k++) g += uw[tid * 128 + k] * basin_coords[k];
      for (int k = 0; k < 64; k++) g += uw[tid * 128 + 64 + k] * aggs[k];
      g = sigmoidf_(g);
      bnew[tid] = basin_coords[tid] * (1.0f - g) + aggs[tid] * g;
    }
    __syncthreads();
    {
      float t = bnew[l] * temp_w[w * 64 + l];
      t = wave_sum64(t);
      if (l == 0) temps[4 + w] = sigmoidf_(t + temp_b[w]) + 0.5f;
    }
  }
}

extern "C" void kernel_launch(void* const* d_in, const int* in_sizes, int n_in,
                              void* d_out, int out_size, void* d_ws, size_t ws_size,
                              hipStream_t stream) {
  const float* bseq         = (const float*)d_in[0];
  const float* basin_coords = (const float*)d_in[1];
  const float* temp_w       = (const float*)d_in[2];
  const float* temp_b       = (const float*)d_in[3];
  const float* rs_layers    = (const float*)d_in[4];
  const float* fb_w         = (const float*)d_in[5];
  const float* fb_b         = (const float*)d_in[6];
  const float* comp_w1      = (const float*)d_in[7];
  const float* comp_b1      = (const float*)d_in[8];
  const float* comp_w2      = (const float*)d_in[9];
  const float* comp_b2      = (const float*)d_in[10];
  const float* upd_w        = (const float*)d_in[11];
  const float* upd_b        = (const float*)d_in[12];
  const float* res_scale    = (const float*)d_in[13];
  float* out = (float*)d_out;

  float* ws = (float*)d_ws;
  float* xA = ws;                         // TD
  float* xB = xA + TD;                    // TD
  float* prevb = xB + TD;                 // 4*TD
  float* fbwT = prevb + 4 * TD;           // 4*128*64
  float* poolPart = fbwT + 32768;         // 48*64
  float* temps = poolPart + 3072;         // 8
  unsigned short* Fb0 = (unsigned short*)(temps + 8);   // 768*128 bf16
  unsigned short* Fb1 = Fb0 + 98304;
  unsigned short* XT0 = Fb1 + 98304;      // 64*768 bf16
  unsigned short* XT1 = XT0 + 49152;

  phaseA_kernel<<<192, 256, 0, stream>>>(bseq, basin_coords, temp_w, temp_b, fb_w,
                                         Fb0, XT0, fbwT, temps);
  // ---- pass 0 ----
  layer_kernel<<<48, 256, 0, stream>>>(bseq, Fb0, XT0, prevb + 0 * TD, Fb1, XT1,
                                       temps, 0, 0, rs_layers, 1,
                                       nullptr, nullptr, nullptr, nullptr,
                                       nullptr, nullptr, nullptr);
  layer_kernel<<<48, 256, 0, stream>>>(prevb + 0 * TD, Fb1, XT1, prevb + 1 * TD, Fb0, XT0,
                                       temps, 1, 1, rs_layers, 1,
                                       nullptr, nullptr, nullptr, nullptr,
                                       nullptr, nullptr, nullptr);
  layer_kernel<<<48, 256, 0, stream>>>(prevb + 1 * TD, Fb0, XT0, prevb + 2 * TD, Fb1, XT1,
                                       temps, 2, 2, rs_layers, 1,
                                       nullptr, nullptr, nullptr, nullptr,
                                       nullptr, nullptr, nullptr);
  layer_kernel<<<48, 256, 0, stream>>>(prevb + 2 * TD, Fb1, XT1, prevb + 3 * TD, Fb0, XT0,
                                       temps, 3, 3, rs_layers, 0,
                                       nullptr, nullptr, nullptr, poolPart,
                                       nullptr, nullptr, nullptr);
  // ---- compress + gate(pass1,l=0) -> xA, Fb0, XT0 ----
  compress_kernel<<<48, 256, 0, stream>>>(prevb + 3 * TD, prevb + 0 * TD,
                                          fbwT + 0 * 8192, fb_b + 0 * 64,
                                          xA, Fb0, XT0, poolPart, basin_coords,
                                          temp_w, temp_b, comp_w1, comp_b1,
                                          comp_w2, comp_b2, upd_w, upd_b, temps);
  // ---- pass 1 ----
  layer_kernel<<<48, 256, 0, stream>>>(xA, Fb0, XT0, xB, Fb1, XT1,
                                       temps, 4, 0, rs_layers, 0,
                                       fbwT + 1 * 8192, fb_b + 1 * 64, prevb + 1 * TD,
                                       nullptr, nullptr, nullptr, nullptr);
  layer_kernel<<<48, 256, 0, stream>>>(xB, Fb1, XT1, xA, Fb0, XT0,
                                       temps, 5, 1, rs_layers, 0,
                                       fbwT + 2 * 8192, fb_b + 2 * 64, prevb + 2 * TD,
                                       nullptr, nullptr, nullptr, nullptr);
  layer_kernel<<<48, 256, 0, stream>>>(xA, Fb0, XT0, xB, Fb1, XT1,
                                       temps, 6, 2, rs_layers, 0,
                                       fbwT + 3 * 8192, fb_b + 3 * 64, prevb + 3 * TD,
                                       nullptr, nullptr, nullptr, nullptr);
  layer_kernel<<<48, 256, 0, stream>>>(xB, Fb1, XT1, xA, Fb0, XT0,
                                       temps, 7, 3, rs_layers, 0,
                                       nullptr, nullptr, nullptr, nullptr,
                                       bseq, res_scale, out);
}

// Round 5
// 157.439 us; speedup vs baseline: 1.2434x; 1.2434x over previous
//
#include <hip/hip_runtime.h>
#include <math.h>

#define T_ 768
#define TD (T_*64)
#define EPSF 1e-8f

typedef __attribute__((ext_vector_type(8))) short short8;
typedef __attribute__((ext_vector_type(4))) float f32x4;

__device__ __forceinline__ float wave_sum64(float v) {
#pragma unroll
  for (int m = 32; m >= 1; m >>= 1) v += __shfl_xor(v, m, 64);
  return v;
}
__device__ __forceinline__ float wave_max64(float v) {
#pragma unroll
  for (int m = 32; m >= 1; m >>= 1) v = fmaxf(v, __shfl_xor(v, m, 64));
  return v;
}
__device__ __forceinline__ float sigmoidf_(float x) { return 1.0f / (1.0f + expf(-x)); }

__device__ __forceinline__ unsigned short f2bf(float x) {
  unsigned int u = __float_as_uint(x);
  u += 0x7fffu + ((u >> 16) & 1u);        // RNE
  return (unsigned short)(u >> 16);
}

// acos(x) for x in [0,1): sqrt(1-x)*poly3, |err|<=6.7e-5 (A-S 4.4.45)
__device__ __forceinline__ float acos_pos(float x) {
  float s = sqrtf(fmaxf(1.0f - x, 0.0f));
  return s * (1.5707288f + x * (-0.2121144f + x * (0.0742610f + x * (-0.0187293f))));
}

// simplex proj + renorm; write feature row f=[sqrt(p), sqrt(eps/2)/sqrt(p)] bf16
__device__ __forceinline__ void feat_bf(float v, int row, int lane,
                                        unsigned short* __restrict__ Fb) {
  float sp = fmaxf(v, 0.0f) + log1pf(expf(-fabsf(v)));
  float s = wave_sum64(sp);
  float p1 = fmaxf(sp / (s + EPSF), EPSF);
  float s2 = wave_sum64(p1);
  float p = p1 / (s2 + EPSF);
  Fb[row * 128 + lane] = f2bf(sqrtf(p));
  Fb[row * 128 + 64 + lane] = f2bf(sqrtf(5e-9f / p));
}

// features(bseq) + XT(bseq) + fb_w transpose + pass-0 temps. grid 192x256.
__global__ void __launch_bounds__(256)
phaseA_kernel(const float* __restrict__ bseq, const float* __restrict__ basin_coords,
              const float* __restrict__ temp_w, const float* __restrict__ temp_b,
              const float* __restrict__ fb_w,
              unsigned short* __restrict__ Fb, unsigned short* __restrict__ XTb,
              float* __restrict__ fbwT, float* __restrict__ temps) {
  int b = blockIdx.x, tid = threadIdx.x, w = tid >> 6, l = tid & 63;
  int row = b * 4 + w;
  float v = bseq[row * 64 + l];
  feat_bf(v, row, l, Fb);
  XTb[l * 768 + row] = f2bf(v);
  if (b < 128) {                         // 128*256 = 32768 = 4*64*128
    int idx = b * 256 + tid;
    int ll = idx >> 13, r = idx & 8191, d = r >> 7, k = r & 127;
    fbwT[ll * 8192 + k * 64 + d] = fb_w[ll * 8192 + d * 128 + k];
  }
  if (b == 191) {
    float t = basin_coords[l] * temp_w[w * 64 + l];
    t = wave_sum64(t);
    if (l == 0) temps[w] = sigmoidf_(t + temp_b[w]) + 0.5f;
  }
}

// Fused layer, 16-wave blocks: MFMA Gram -> acos -> softmax -> K-split MFMA PV
// -> residual -> tail. 48 blocks x 1024 thr, 16 rows per block, 4 waves/SIMD.
__global__ void __launch_bounds__(1024)
layer_kernel(const float* __restrict__ xin,
             const unsigned short* __restrict__ Fb_in,
             const unsigned short* __restrict__ XTb_in,
             float* __restrict__ xout,
             unsigned short* __restrict__ Fb_out,
             unsigned short* __restrict__ XTb_out,
             const float* __restrict__ temps, int tidx, int lidx,
             const float* __restrict__ rs_layers, int doFeat,
             const float* __restrict__ WTnext, const float* __restrict__ bnext,
             const float* __restrict__ prevNext,
             float* __restrict__ poolPart,
             const float* __restrict__ bseq, const float* __restrict__ res_scale,
             float* __restrict__ finalOut) {
  __shared__ __align__(16) float lg[16][776];          // logits
  __shared__ __align__(16) unsigned short Pl[16][776]; // P bf16
  __shared__ __align__(16) float pvp[4][16][68];       // PV partials per K-quarter
  __shared__ __align__(16) float xs[16][64];
  __shared__ __align__(16) float ps_s[16][64];
  int tid = threadIdx.x, w = tid >> 6, l = tid & 63;
  int lr = l & 15, lk = l >> 4;
  int i0 = blockIdx.x * 16;

  if (WTnext)                             // stage prev row (used in gate tail)
    ps_s[w][l] = prevNext[(i0 + w) * 64 + l];

  // A-frags: lane holds F row i0+lr, k = ks*32 + lk*8 .. +7
  const short8* arow = reinterpret_cast<const short8*>(Fb_in + (i0 + lr) * 128);
  short8 afr[4];
#pragma unroll
  for (int ks = 0; ks < 4; ks++) afr[ks] = arow[ks * 4 + lk];

  float inv_t = 1.0f / fmaxf(temps[tidx], 1e-6f);

  // ---- QK Gram: wave w owns j-tiles w, w+16, w+32 ----
#pragma unroll
  for (int jj = 0; jj < 3; jj++) {
    int jt = w + jj * 16;
    const short8* brow = reinterpret_cast<const short8*>(Fb_in + (jt * 16 + lr) * 128);
    f32x4 acc = {0.f, 0.f, 0.f, 0.f};
#pragma unroll
    for (int ks = 0; ks < 4; ks++)
      acc = __builtin_amdgcn_mfma_f32_16x16x32_bf16(afr[ks], brow[ks * 4 + lk], acc, 0, 0, 0);
    // C layout: col = lane&15 (j within tile), row = (lane>>4)*4 + r (i)
#pragma unroll
    for (int r = 0; r < 4; r++) {
      float inner = fminf(fmaxf(acc[r], 0.0f), 1.0f - 1e-6f);
      lg[lk * 4 + r][jt * 16 + lr] = -2.0f * acos_pos(inner) * inv_t;
    }
  }
  __syncthreads();

  // ---- softmax: wave w handles row w ----
  {
    float v[12];
    float m = -1e30f;
#pragma unroll
    for (int q = 0; q < 12; q++) { v[q] = lg[w][l + 64 * q]; m = fmaxf(m, v[q]); }
    m = wave_max64(m);
    float s = 0.f;
#pragma unroll
    for (int q = 0; q < 12; q++) { v[q] = expf(v[q] - m); s += v[q]; }
    s = wave_sum64(s);
    float is = 1.0f / s;
#pragma unroll
    for (int q = 0; q < 12; q++) Pl[w][l + 64 * q] = f2bf(v[q] * is);
  }
  __syncthreads();

  // ---- PV: wave (cg=w&3, kq=w>>2): cols cg*16..+15, K-chunk kq*192..+191 ----
  {
    int cg = w & 3, kq = w >> 2;
    f32x4 pacc = {0.f, 0.f, 0.f, 0.f};
    const short8* xtrow =
        reinterpret_cast<const short8*>(XTb_in + (cg * 16 + lr) * 768 + kq * 192);
#pragma unroll
    for (int ks = 0; ks < 6; ks++) {
      short8 pa = *reinterpret_cast<const short8*>(&Pl[lr][kq * 192 + ks * 32 + lk * 8]);
      pacc = __builtin_amdgcn_mfma_f32_16x16x32_bf16(pa, xtrow[ks * 4 + lk], pacc, 0, 0, 0);
    }
#pragma unroll
    for (int r = 0; r < 4; r++) pvp[kq][lk * 4 + r][cg * 16 + lr] = pacc[r];
  }
  __syncthreads();

  // ---- residual: wave w row w ----
  {
    float pv = pvp[0][w][l] + pvp[1][w][l] + pvp[2][w][l] + pvp[3][w][l];
    float xi = xin[(i0 + w) * 64 + l];
    float rs = rs_layers[lidx];
    xs[w][l] = xi + rs * (pv - xi);
  }
  __syncthreads();

  // ---- tails: wave w row w ----
  int row = i0 + w;
  float xo = xs[w][l];
  if (finalOut) {
    float sc = 0.01f * res_scale[0];
    finalOut[row * 64 + l] = xo + sc * (xo - bseq[row * 64 + l]);
    return;
  }
  if (WTnext) {                          // feedback gate for NEXT ref-layer
    float a = bnext[l];
#pragma unroll 8
    for (int k = 0; k < 64; k++) a += xs[w][k] * WTnext[k * 64 + l];
#pragma unroll 8
    for (int k = 0; k < 64; k++) a += ps_s[w][k] * WTnext[(64 + k) * 64 + l];
    float g = sigmoidf_(a);
    float xn = xo * g + ps_s[w][l] * (1.0f - g);
    xout[row * 64 + l] = xn;
    XTb_out[l * 768 + row] = f2bf(xn);
    feat_bf(xn, row, l, Fb_out);
  } else {
    xout[row * 64 + l] = xo;
    if (doFeat) {
      XTb_out[l * 768 + row] = f2bf(xo);
      feat_bf(xo, row, l, Fb_out);
    }
    if (poolPart && w == 0) {
      float s = 0.f;
#pragma unroll
      for (int r2 = 0; r2 < 16; r2++) s += xs[r2][l];
      poolPart[blockIdx.x * 64 + l] = s;
    }
  }
}

// gate(pass1,l=0) on 48 blocks; block 0 also: pool reduce -> MLP -> basin -> temps[4..7]
__global__ void __launch_bounds__(256)
compress_kernel(const float* __restrict__ xin, const float* __restrict__ prev0,
                const float* __restrict__ WT0, const float* __restrict__ b0,
                float* __restrict__ xout, unsigned short* __restrict__ Fb_out,
                unsigned short* __restrict__ XTb_out,
                const float* __restrict__ poolPart,
                const float* __restrict__ basin_coords,
                const float* __restrict__ temp_w, const float* __restrict__ temp_b,
                const float* __restrict__ w1, const float* __restrict__ b1,
                const float* __restrict__ w2, const float* __restrict__ b2,
                const float* __restrict__ uw, const float* __restrict__ ub,
                float* __restrict__ temps) {
  __shared__ float xs[16][64], ps_s[16][64];
  __shared__ float pooled[64], h1s[32], aggs[64], bnew[64];
  int tid = threadIdx.x, w = tid >> 6, l = tid & 63;
  int i0 = blockIdx.x * 16;
#pragma unroll
  for (int rr = 0; rr < 4; rr++) {
    int row = w * 4 + rr;
    xs[row][l] = xin[(i0 + row) * 64 + l];
    ps_s[row][l] = prev0[(i0 + row) * 64 + l];
  }
  __syncthreads();
  float a[4];
#pragma unroll
  for (int rr = 0; rr < 4; rr++) a[rr] = b0[l];
  for (int k = 0; k < 64; k++) {
    float wv = WT0[k * 64 + l];
#pragma unroll
    for (int rr = 0; rr < 4; rr++) a[rr] += xs[w * 4 + rr][k] * wv;
  }
  for (int k = 0; k < 64; k++) {
    float wv = WT0[(64 + k) * 64 + l];
#pragma unroll
    for (int rr = 0; rr < 4; rr++) a[rr] += ps_s[w * 4 + rr][k] * wv;
  }
#pragma unroll
  for (int rr = 0; rr < 4; rr++) {
    int row = w * 4 + rr;
    float g = sigmoidf_(a[rr]);
    float xn = xs[row][l] * g + ps_s[row][l] * (1.0f - g);
    xout[(i0 + row) * 64 + l] = xn;
    XTb_out[l * 768 + i0 + row] = f2bf(xn);
    feat_bf(xn, i0 + row, l, Fb_out);
  }
  if (blockIdx.x == 0) {
    __syncthreads();
    if (w == 0) {
      float s = 0.f;
      for (int bb = 0; bb < 48; bb++) s += poolPart[bb * 64 + l];
      pooled[l] = s * (1.0f / 768.0f);
    }
    __syncthreads();
    if (tid < 32) {
      float h = b1[tid];
      for (int k = 0; k < 64; k++) h += w1[tid * 64 + k] * pooled[k];
      h1s[tid] = tanhf(h);
    }
    __syncthreads();
    if (tid < 64) {
      float h = b2[tid];
      for (int k = 0; k < 32; k++) h += w2[tid * 32 + k] * h1s[k];
      aggs[tid] = tanhf(h);
    }
    __syncthreads();
    if (tid < 64) {
      float g = ub[tid];
      for (int k = 0; k < 64; k++) g += uw[tid * 128 + k] * basin_coords[k];
      for (int k = 0; k < 64; k++) g += uw[tid * 128 + 64 + k] * aggs[k];
      g = sigmoidf_(g);
      bnew[tid] = basin_coords[tid] * (1.0f - g) + aggs[tid] * g;
    }
    __syncthreads();
    {
      float t = bnew[l] * temp_w[w * 64 + l];
      t = wave_sum64(t);
      if (l == 0) temps[4 + w] = sigmoidf_(t + temp_b[w]) + 0.5f;
    }
  }
}

extern "C" void kernel_launch(void* const* d_in, const int* in_sizes, int n_in,
                              void* d_out, int out_size, void* d_ws, size_t ws_size,
                              hipStream_t stream) {
  const float* bseq         = (const float*)d_in[0];
  const float* basin_coords = (const float*)d_in[1];
  const float* temp_w       = (const float*)d_in[2];
  const float* temp_b       = (const float*)d_in[3];
  const float* rs_layers    = (const float*)d_in[4];
  const float* fb_w         = (const float*)d_in[5];
  const float* fb_b         = (const float*)d_in[6];
  const float* comp_w1      = (const float*)d_in[7];
  const float* comp_b1      = (const float*)d_in[8];
  const float* comp_w2      = (const float*)d_in[9];
  const float* comp_b2      = (const float*)d_in[10];
  const float* upd_w        = (const float*)d_in[11];
  const float* upd_b        = (const float*)d_in[12];
  const float* res_scale    = (const float*)d_in[13];
  float* out = (float*)d_out;

  float* ws = (float*)d_ws;
  float* xA = ws;                         // TD
  float* xB = xA + TD;                    // TD
  float* prevb = xB + TD;                 // 4*TD
  float* fbwT = prevb + 4 * TD;           // 4*128*64
  float* poolPart = fbwT + 32768;         // 48*64
  float* temps = poolPart + 3072;         // 8
  unsigned short* Fb0 = (unsigned short*)(temps + 8);   // 768*128 bf16
  unsigned short* Fb1 = Fb0 + 98304;
  unsigned short* XT0 = Fb1 + 98304;      // 64*768 bf16
  unsigned short* XT1 = XT0 + 49152;

  phaseA_kernel<<<192, 256, 0, stream>>>(bseq, basin_coords, temp_w, temp_b, fb_w,
                                         Fb0, XT0, fbwT, temps);
  // ---- pass 0 ----
  layer_kernel<<<48, 1024, 0, stream>>>(bseq, Fb0, XT0, prevb + 0 * TD, Fb1, XT1,
                                        temps, 0, 0, rs_layers, 1,
                                        nullptr, nullptr, nullptr, nullptr,
                                        nullptr, nullptr, nullptr);
  layer_kernel<<<48, 1024, 0, stream>>>(prevb + 0 * TD, Fb1, XT1, prevb + 1 * TD, Fb0, XT0,
                                        temps, 1, 1, rs_layers, 1,
                                        nullptr, nullptr, nullptr, nullptr,
                                        nullptr, nullptr, nullptr);
  layer_kernel<<<48, 1024, 0, stream>>>(prevb + 1 * TD, Fb0, XT0, prevb + 2 * TD, Fb1, XT1,
                                        temps, 2, 2, rs_layers, 1,
                                        nullptr, nullptr, nullptr, nullptr,
                                        nullptr, nullptr, nullptr);
  layer_kernel<<<48, 1024, 0, stream>>>(prevb + 2 * TD, Fb1, XT1, prevb + 3 * TD, Fb0, XT0,
                                        temps, 3, 3, rs_layers, 0,
                                        nullptr, nullptr, nullptr, poolPart,
                                        nullptr, nullptr, nullptr);
  // ---- compress + gate(pass1,l=0) -> xA, Fb0, XT0 ----
  compress_kernel<<<48, 256, 0, stream>>>(prevb + 3 * TD, prevb + 0 * TD,
                                          fbwT + 0 * 8192, fb_b + 0 * 64,
                                          xA, Fb0, XT0, poolPart, basin_coords,
                                          temp_w, temp_b, comp_w1, comp_b1,
                                          comp_w2, comp_b2, upd_w, upd_b, temps);
  // ---- pass 1 ----
  layer_kernel<<<48, 1024, 0, stream>>>(xA, Fb0, XT0, xB, Fb1, XT1,
                                        temps, 4, 0, rs_layers, 0,
                                        fbwT + 1 * 8192, fb_b + 1 * 64, prevb + 1 * TD,
                                        nullptr, nullptr, nullptr, nullptr);
  layer_kernel<<<48, 1024, 0, stream>>>(xB, Fb1, XT1, xA, Fb0, XT0,
                                        temps, 5, 1, rs_layers, 0,
                                        fbwT + 2 * 8192, fb_b + 2 * 64, prevb + 2 * TD,
                                        nullptr, nullptr, nullptr, nullptr);
  layer_kernel<<<48, 1024, 0, stream>>>(xA, Fb0, XT0, xB, Fb1, XT1,
                                        temps, 6, 2, rs_layers, 0,
                                        fbwT + 3 * 8192, fb_b + 3 * 64, prevb + 3 * TD,
                                        nullptr, nullptr, nullptr, nullptr);
  layer_kernel<<<48, 1024, 0, stream>>>(xB, Fb1, XT1, xA, Fb0, XT0,
                                        temps, 7, 3, rs_layers, 0,
                                        nullptr, nullptr, nullptr, nullptr,
                                        bseq, res_scale, out);
}